// Round 1
// baseline (624.223 us; speedup 1.0000x reference)
//
#include <hip/hip_runtime.h>

typedef unsigned short u16;
typedef __bf16 bf16x8 __attribute__((ext_vector_type(8)));
typedef float f32x4 __attribute__((ext_vector_type(4)));

#define MFMA16(A,B,C) __builtin_amdgcn_mfma_f32_16x16x32_bf16((A),(B),(C),0,0,0)

__device__ __forceinline__ u16 f2b(float f){
  union { float f; unsigned u; } X; X.f = f;
  unsigned r = X.u + 0x7FFFu + ((X.u >> 16) & 1u);
  return (u16)(r >> 16);
}
__device__ __forceinline__ float b2f(u16 h){
  union { unsigned u; float f; } X; X.u = ((unsigned)h) << 16; return X.f;
}
__device__ __forceinline__ bf16x8 ld_frag(const u16* p){
  union { uint4 u; bf16x8 v; } U; U.u = *(const uint4*)p; return U.v;
}
__device__ __forceinline__ bf16x8 zero_frag(){
  union { uint4 u; bf16x8 v; } U; U.u = make_uint4(0u,0u,0u,0u); return U.v;
}

// ---------------- K0: weight prep (transpose + bf16 cvt) ----------------
// w11t/w7t/w1t: [tap][oc(16)][ci(256)]; kwt:[oc32][ci256]; vwt:[co256][ci256];
// w2t:[co256][k160] with k=ci*9+tap (conv2_w native order), padded 144..159 = 0.
__global__ __launch_bounds__(256) void k_prep_w(
    const float* __restrict__ dw1, const float* __restrict__ dw2,
    const float* __restrict__ cw1, const float* __restrict__ kw,
    const float* __restrict__ vw,  const float* __restrict__ cw2,
    u16* __restrict__ w7t, u16* __restrict__ w11t, u16* __restrict__ w1t,
    u16* __restrict__ kwt, u16* __restrict__ vwt, u16* __restrict__ w2t){
  int i = blockIdx.x * 256 + threadIdx.x;
  const int N11 = 121*4096, N7 = 49*4096, N1 = 9*4096, NK = 8192, NV = 65536, N2 = 40960;
  if(i < N11){ int tap=i>>12, r=i&4095, oc=r>>8, ci=r&255; w11t[i] = f2b(dw2[(oc*256+ci)*121 + tap]); return; }
  i -= N11;
  if(i < N7){ int tap=i>>12, r=i&4095, oc=r>>8, ci=r&255; w7t[i] = f2b(dw1[(oc*256+ci)*49 + tap]); return; }
  i -= N7;
  if(i < N1){ int tap=i>>12, r=i&4095, oc=r>>8, ci=r&255; w1t[i] = f2b(cw1[(oc*256+ci)*9 + tap]); return; }
  i -= N1;
  if(i < NK){ kwt[i] = f2b(kw[i]); return; }
  i -= NK;
  if(i < NV){ vwt[i] = f2b(vw[i]); return; }
  i -= NV;
  if(i < N2){ int co = i/160, kk = i - co*160; w2t[i] = (kk < 144) ? f2b(cw2[co*144 + kk]) : (u16)0; return; }
}

// ---------------- K1: x NCHW fp32 -> xt[b][m][ci] bf16 (pixel-major) ----------------
__global__ __launch_bounds__(256) void k_prep_x(const float* __restrict__ x, u16* __restrict__ xt){
  __shared__ float tile[32][33];
  const int bid = blockIdx.x;
  const int b = bid >> 10, rem = bid & 1023;
  const int c0 = (rem >> 7) << 5, m0 = (rem & 127) << 5;
  const int t = threadIdx.x;
  { const int cg = t >> 5, mm = t & 31;
    #pragma unroll
    for(int i=0;i<4;i++)
      tile[cg*4+i][mm] = x[((size_t)(b*256 + c0 + cg*4 + i) << 12) + m0 + mm];
  }
  __syncthreads();
  { const int rg = t >> 5, cc = t & 31;
    #pragma unroll
    for(int i=0;i<4;i++){
      int m = m0 + rg*4 + i;
      xt[((size_t)(b*4096 + m) << 8) + c0 + cc] = f2b(tile[cc][rg*4+i]);
    }
  }
}

// ---------------- K2: fused conv7 + conv11 (-> q_t) + conv1+silu (-> t1), implicit GEMM MFMA ----------------
// wg = (b, row y). wave = 16-px D-tile. A = xt shifted window, B = weight tables.
__global__ __launch_bounds__(256) void k_qconv(
    const u16* __restrict__ xt, const u16* __restrict__ w7t, const u16* __restrict__ w11t,
    const u16* __restrict__ w1t, const float* __restrict__ b7, const float* __restrict__ b11,
    const float* __restrict__ b1, u16* __restrict__ q_t, u16* __restrict__ t1){
  const int b = blockIdx.x >> 6, y = blockIdx.x & 63;
  const int wv = threadIdx.x >> 6, lane = threadIdx.x & 63;
  const int col = lane & 15, quad = lane >> 4;
  const int pxb = wv << 4;
  f32x4 a7 = {0.f,0.f,0.f,0.f}, a11 = {0.f,0.f,0.f,0.f}, a1 = {0.f,0.f,0.f,0.f};
  const u16* xb = xt + ((size_t)(b*4096) << 8);
  #pragma unroll 1
  for(int ch = 0; ch < 8; ++ch){
    const int cio = ch*32 + quad*8;
    #pragma unroll 1
    for(int dy = 0; dy < 11; ++dy){
      const int ry = y + dy - 5;
      if((unsigned)ry >= 64u) continue;
      const u16* xr = xb + ((ry*64) << 8) + cio;
      const int wrow = dy * 11;
      #pragma unroll
      for(int dx = 0; dx < 11; ++dx){
        const int xx = pxb + col + dx - 5;
        bf16x8 a = zero_frag();
        if((unsigned)xx < 64u) a = ld_frag(xr + (xx << 8));
        bf16x8 wf11 = ld_frag(w11t + ((size_t)(wrow + dx) << 12) + (col << 8) + cio);
        a11 = MFMA16(a, wf11, a11);
        if((unsigned)(dy-2) <= 6u && (unsigned)(dx-2) <= 6u){
          bf16x8 wf7 = ld_frag(w7t + ((size_t)((dy-2)*7 + (dx-2)) << 12) + (col << 8) + cio);
          a7 = MFMA16(a, wf7, a7);
        }
        if((unsigned)(dy-4) <= 2u && (unsigned)(dx-4) <= 2u){
          bf16x8 wf1 = ld_frag(w1t + ((size_t)((dy-4)*3 + (dx-4)) << 12) + (col << 8) + cio);
          a1 = MFMA16(a, wf1, a1);
        }
      }
    }
  }
  // epilogue: D row = px (quad*4+reg), col = oc
  const int m0 = (y << 6) + pxb + (quad << 2);
  const float bb7 = b7[col], bb11 = b11[col], bb1 = b1[col];
  #pragma unroll
  for(int r = 0; r < 4; ++r){
    const int m = b*4096 + m0 + r;
    q_t[m*32 + col]      = f2b(a7[r]  + bb7);
    q_t[m*32 + 16 + col] = f2b(a11[r] + bb11);
    float v = a1[r] + bb1;
    t1[m*16 + col] = f2b(v / (1.f + __expf(-v)));
  }
}

// ---------------- K3: 1x1 convs: k_t[b][m][32] (pixel-major) and v_c[b][c][m] (channel-major) ----------------
__global__ __launch_bounds__(256) void k_kv(
    const u16* __restrict__ xt, const u16* __restrict__ vwt, const u16* __restrict__ kwt,
    const float* __restrict__ vb, const float* __restrict__ kb,
    u16* __restrict__ v_c, u16* __restrict__ k_t){
  const int b = blockIdx.x >> 6, blk = blockIdx.x & 63;
  const int wv = threadIdx.x >> 6, lane = threadIdx.x & 63;
  const int col = lane & 15, quad = lane >> 4;
  const int m0 = (blk << 6) + (wv << 4);
  f32x4 z = {0.f,0.f,0.f,0.f};
  f32x4 av[16], ak[2];
  #pragma unroll
  for(int i=0;i<16;i++) av[i] = z;
  ak[0] = z; ak[1] = z;
  const u16* xrow = xt + ((size_t)(b*4096 + m0 + col) << 8);
  #pragma unroll 1
  for(int ch = 0; ch < 8; ++ch){
    const int cio = ch*32 + quad*8;
    bf16x8 xf = ld_frag(xrow + cio);
    #pragma unroll
    for(int ct = 0; ct < 16; ++ct){
      bf16x8 wf = ld_frag(vwt + ((ct*16 + col) << 8) + cio);
      av[ct] = MFMA16(wf, xf, av[ct]);   // A = value_w (rows=c), B = xt (cols=px)
    }
    #pragma unroll
    for(int kt = 0; kt < 2; ++kt){
      bf16x8 kf = ld_frag(kwt + ((kt*16 + col) << 8) + cio);
      ak[kt] = MFMA16(xf, kf, ak[kt]);   // A = xt (rows=px), B = key_w (cols=oc)
    }
  }
  #pragma unroll
  for(int ct = 0; ct < 16; ++ct){
    #pragma unroll
    for(int r = 0; r < 4; ++r){
      const int c = ct*16 + quad*4 + r;
      v_c[((size_t)(b*256 + c) << 12) + m0 + col] = f2b(av[ct][r] + vb[c]);
    }
  }
  #pragma unroll
  for(int kt = 0; kt < 2; ++kt){
    #pragma unroll
    for(int r = 0; r < 4; ++r){
      const int m = b*4096 + m0 + quad*4 + r;
      k_t[m*32 + kt*16 + col] = f2b(ak[kt][r] + kb[kt*16 + col]);
    }
  }
}

// ---------------- K4: flash attention. TQ=64 queries/wg, TK=64 keys/tile, 8 waves ----------------
__global__ __launch_bounds__(512) void k_attn(
    const u16* __restrict__ q_t, const u16* __restrict__ k_t,
    const u16* __restrict__ v_c, float* __restrict__ O){
  __shared__ __align__(16) float S[64][68];
  __shared__ __align__(16) u16 P[64][72];
  __shared__ float alpha_l[64];
  __shared__ float l_l[64];
  const int b = blockIdx.x >> 6, q0 = (blockIdx.x & 63) << 6;
  const int t = threadIdx.x, wv = t >> 6, lane = t & 63, col = lane & 15, quad = lane >> 4;
  const int qtw = wv >> 1;          // this wave's q-tile for QK
  const int cb = wv << 5;           // this wave's 32-channel slice for PV
  const int sr = t >> 3, sc = t & 7; // softmax row / col-group
  const bf16x8 qf = ld_frag(q_t + (size_t)(b*4096 + q0 + qtw*16 + col) * 32 + quad*8);
  const f32x4 z = {0.f,0.f,0.f,0.f};
  f32x4 acc[4][2];
  #pragma unroll
  for(int qq=0;qq<4;qq++){ acc[qq][0] = z; acc[qq][1] = z; }
  float m_i = -1e30f, l_i = 0.f;
  const u16* kbase = k_t + (size_t)(b*4096) * 32;
  const u16* vbase = v_c + ((size_t)(b*256 + cb) << 12);
  for(int kt = 0; kt < 64; ++kt){
    const int mm0 = kt << 6;
    { // --- QK: each wave computes 2 of the 16 S-tiles ---
      const int mt = (wv & 1) << 1;
      #pragma unroll
      for(int mi = 0; mi < 2; ++mi){
        bf16x8 kf = ld_frag(kbase + (size_t)(mm0 + (mt+mi)*16 + col) * 32 + quad*8);
        f32x4 s = MFMA16(qf, kf, z);
        const int rr = qtw*16 + quad*4, cc2 = (mt+mi)*16 + col;
        S[rr+0][cc2] = s[0]; S[rr+1][cc2] = s[1]; S[rr+2][cc2] = s[2]; S[rr+3][cc2] = s[3];
      }
    }
    __syncthreads();
    { // --- online softmax: 8 threads per row ---
      float4 s0 = *(const float4*)&S[sr][sc*8];
      float4 s1 = *(const float4*)&S[sr][sc*8 + 4];
      float mx = fmaxf(fmaxf(fmaxf(s0.x,s0.y),fmaxf(s0.z,s0.w)),
                       fmaxf(fmaxf(s1.x,s1.y),fmaxf(s1.z,s1.w)));
      mx = fmaxf(mx, __shfl_xor(mx,1)); mx = fmaxf(mx, __shfl_xor(mx,2)); mx = fmaxf(mx, __shfl_xor(mx,4));
      const float mnew = fmaxf(m_i, mx);
      const float al = __expf(m_i - mnew);
      float p0 = __expf(s0.x - mnew), p1 = __expf(s0.y - mnew), p2 = __expf(s0.z - mnew), p3 = __expf(s0.w - mnew);
      float p4 = __expf(s1.x - mnew), p5 = __expf(s1.y - mnew), p6 = __expf(s1.z - mnew), p7 = __expf(s1.w - mnew);
      float sum = ((p0+p1)+(p2+p3)) + ((p4+p5)+(p6+p7));
      sum += __shfl_xor(sum,1); sum += __shfl_xor(sum,2); sum += __shfl_xor(sum,4);
      l_i = l_i * al + sum; m_i = mnew;
      union { u16 s[8]; uint4 u; } PW;
      PW.s[0]=f2b(p0); PW.s[1]=f2b(p1); PW.s[2]=f2b(p2); PW.s[3]=f2b(p3);
      PW.s[4]=f2b(p4); PW.s[5]=f2b(p5); PW.s[6]=f2b(p6); PW.s[7]=f2b(p7);
      *(uint4*)&P[sr][sc*8] = PW.u;
      if(sc == 0) alpha_l[sr] = al;
    }
    __syncthreads();
    { // --- PV: wave owns 32 channels; A = P (rows=q), B = v_c (cols=c) ---
      bf16x8 pa[4][2];
      #pragma unroll
      for(int qq=0; qq<4; ++qq)
        #pragma unroll
        for(int chh=0; chh<2; ++chh)
          pa[qq][chh] = ld_frag(&P[qq*16 + col][chh*32 + quad*8]);
      #pragma unroll
      for(int qq=0; qq<4; ++qq){
        f32x4 asc;
        asc[0] = alpha_l[qq*16 + quad*4 + 0];
        asc[1] = alpha_l[qq*16 + quad*4 + 1];
        asc[2] = alpha_l[qq*16 + quad*4 + 2];
        asc[3] = alpha_l[qq*16 + quad*4 + 3];
        acc[qq][0] *= asc; acc[qq][1] *= asc;
      }
      #pragma unroll
      for(int ct = 0; ct < 2; ++ct){
        #pragma unroll
        for(int chh = 0; chh < 2; ++chh){
          bf16x8 vf = ld_frag(vbase + ((size_t)(ct*16 + col) << 12) + mm0 + chh*32 + quad*8);
          #pragma unroll
          for(int qq = 0; qq < 4; ++qq)
            acc[qq][ct] = MFMA16(pa[qq][chh], vf, acc[qq][ct]);
        }
      }
    }
  }
  if(sc == 0) l_l[sr] = l_i;
  __syncthreads();
  #pragma unroll
  for(int qq = 0; qq < 4; ++qq){
    #pragma unroll
    for(int r = 0; r < 4; ++r){
      const float inv = 1.f / l_l[qq*16 + quad*4 + r];
      const int n = q0 + qq*16 + quad*4 + r;
      float* orow = O + ((size_t)(b*4096 + n) << 8) + cb + col;
      orow[0]  = acc[qq][0][r] * inv;
      orow[16] = acc[qq][1][r] * inv;
    }
  }
}

// ---------------- K5: conv2 (3x3, 16->256) via LDS im2col + pooled partial sums ----------------
__global__ __launch_bounds__(256) void k_conv2(
    const u16* __restrict__ t1, const u16* __restrict__ w2t, const float* __restrict__ b2,
    u16* __restrict__ y_t, float* __restrict__ pooled){
  __shared__ __align__(16) u16 im[64][168];
  __shared__ float pool_l[256];
  const int b = blockIdx.x >> 6, y = blockIdx.x & 63;
  const int t = threadIdx.x;
  pool_l[t] = 0.f;
  const u16* t1b = t1 + ((size_t)(b*4096) << 4);
  for(int e = t; e < 64*144; e += 256){
    int px = e / 144, kk = e - px*144;
    int ci = kk / 9, tp = kk - ci*9;
    int ky = tp / 3, kx = tp - ky*3;
    int ryy = y + ky - 1, rxx = px + kx - 1;
    u16 val = 0;
    if((unsigned)ryy < 64u && (unsigned)rxx < 64u) val = t1b[((ryy<<6) + rxx)*16 + ci];
    im[px][kk] = val;
  }
  for(int e = t; e < 64*24; e += 256){ int px = e/24; im[px][144 + (e - px*24)] = 0; }
  __syncthreads();
  const int wv = t >> 6, lane = t & 63, col = lane & 15, quad = lane >> 4;
  const f32x4 z = {0.f,0.f,0.f,0.f};
  f32x4 acc[16];
  #pragma unroll
  for(int i=0;i<16;i++) acc[i] = z;
  #pragma unroll
  for(int ch = 0; ch < 5; ++ch){
    bf16x8 af = ld_frag(&im[wv*16 + col][ch*32 + quad*8]);
    #pragma unroll
    for(int nt = 0; nt < 16; ++nt){
      bf16x8 wf = ld_frag(w2t + (nt*16 + col)*160 + ch*32 + quad*8);
      acc[nt] = MFMA16(af, wf, acc[nt]);
    }
  }
  const int m0 = (y << 6) + (wv << 4) + (quad << 2);
  #pragma unroll
  for(int nt = 0; nt < 16; ++nt){
    const int c = nt*16 + col;
    const float bias = b2[c];
    float s = 0.f;
    #pragma unroll
    for(int r = 0; r < 4; ++r){
      float v = acc[nt][r] + bias;
      y_t[((size_t)(b*4096 + m0 + r) << 8) + c] = f2b(v);
      s += v;
    }
    s += __shfl_xor(s, 16); s += __shfl_xor(s, 32);
    if(quad == 0) atomicAdd(&pool_l[c], s);
  }
  __syncthreads();
  atomicAdd(&pooled[b*256 + t], pool_l[t]);
}

// ---------------- K6: SE gate: g[b][c] = sigmoid(se_w @ (pooled/4096) + se_b) ----------------
__global__ __launch_bounds__(256) void k_se(
    const float* __restrict__ pooled, const float* __restrict__ sew,
    const float* __restrict__ seb, float* __restrict__ g){
  __shared__ __align__(16) float pl[256];
  const int b = blockIdx.x, t = threadIdx.x;
  pl[t] = pooled[b*256 + t] * (1.f/4096.f);
  __syncthreads();
  float a = seb[t];
  const float4* wr = (const float4*)(sew + t*256);
  const float4* pr = (const float4*)pl;
  #pragma unroll 4
  for(int i = 0; i < 64; ++i){
    float4 w4 = wr[i]; float4 p4 = pr[i];
    a += w4.x*p4.x + w4.y*p4.y + w4.z*p4.z + w4.w*p4.w;
  }
  g[b*256 + t] = 1.f / (1.f + __expf(-a));
}

// ---------------- K7: final combine, pixel-major -> NCHW ----------------
__global__ __launch_bounds__(256) void k_final(
    const float* __restrict__ O, const u16* __restrict__ y_t, const float* __restrict__ x,
    const float* __restrict__ g, const float* __restrict__ g1p, const float* __restrict__ g2p,
    float* __restrict__ out){
  __shared__ float tO[32][65];
  __shared__ float tY[32][65];
  const int bid = blockIdx.x;
  const int b = bid >> 9, rem = bid & 511;
  const int c0 = (rem >> 6) << 5, m0 = (rem & 63) << 6;
  const int t = threadIdx.x;
  const float g1 = g1p[0], g2 = g2p[0];
  { const int ml = t >> 2, cg = (t & 3) << 3;
    const float* orow = O + ((size_t)(b*4096 + m0 + ml) << 8) + c0 + cg;
    float4 o0 = *(const float4*)orow, o1 = *(const float4*)(orow + 4);
    tO[cg+0][ml]=o0.x; tO[cg+1][ml]=o0.y; tO[cg+2][ml]=o0.z; tO[cg+3][ml]=o0.w;
    tO[cg+4][ml]=o1.x; tO[cg+5][ml]=o1.y; tO[cg+6][ml]=o1.z; tO[cg+7][ml]=o1.w;
    const u16* yrow = y_t + ((size_t)(b*4096 + m0 + ml) << 8) + c0 + cg;
    uint4 yu = *(const uint4*)yrow;
    tY[cg+0][ml]=b2f((u16)(yu.x & 0xffffu)); tY[cg+1][ml]=b2f((u16)(yu.x >> 16));
    tY[cg+2][ml]=b2f((u16)(yu.y & 0xffffu)); tY[cg+3][ml]=b2f((u16)(yu.y >> 16));
    tY[cg+4][ml]=b2f((u16)(yu.z & 0xffffu)); tY[cg+5][ml]=b2f((u16)(yu.z >> 16));
    tY[cg+6][ml]=b2f((u16)(yu.w & 0xffffu)); tY[cg+7][ml]=b2f((u16)(yu.w >> 16));
  }
  __syncthreads();
  { const int cl = t >> 3, mg = (t & 7) << 3;
    const int c = c0 + cl;
    const float gate = g[b*256 + c] * g2;
    const float* xrow = x + ((size_t)(b*256 + c) << 12) + m0 + mg;
    float* orow = out + ((size_t)(b*256 + c) << 12) + m0 + mg;
    float4 x0 = *(const float4*)xrow, x1 = *(const float4*)(xrow + 4);
    float4 r0, r1;
    r0.x = g1*tO[cl][mg+0] + gate*tY[cl][mg+0] + x0.x;
    r0.y = g1*tO[cl][mg+1] + gate*tY[cl][mg+1] + x0.y;
    r0.z = g1*tO[cl][mg+2] + gate*tY[cl][mg+2] + x0.z;
    r0.w = g1*tO[cl][mg+3] + gate*tY[cl][mg+3] + x0.w;
    r1.x = g1*tO[cl][mg+4] + gate*tY[cl][mg+4] + x1.x;
    r1.y = g1*tO[cl][mg+5] + gate*tY[cl][mg+5] + x1.y;
    r1.z = g1*tO[cl][mg+6] + gate*tY[cl][mg+6] + x1.z;
    r1.w = g1*tO[cl][mg+7] + gate*tY[cl][mg+7] + x1.w;
    *(float4*)orow = r0;
    *(float4*)(orow + 4) = r1;
  }
}

extern "C" void kernel_launch(void* const* d_in, const int* in_sizes, int n_in,
                              void* d_out, int out_size, void* d_ws, size_t ws_size,
                              hipStream_t stream){
  (void)in_sizes; (void)n_in; (void)out_size; (void)ws_size;
  const float* x    = (const float*)d_in[0];
  const float* dw1w = (const float*)d_in[1];
  const float* dw1b = (const float*)d_in[2];
  const float* dw2w = (const float*)d_in[3];
  const float* dw2b = (const float*)d_in[4];
  const float* keyw = (const float*)d_in[5];
  const float* keyb = (const float*)d_in[6];
  const float* valw = (const float*)d_in[7];
  const float* valb = (const float*)d_in[8];
  const float* c1w  = (const float*)d_in[9];
  const float* c1b  = (const float*)d_in[10];
  const float* c2w  = (const float*)d_in[11];
  const float* c2b  = (const float*)d_in[12];
  const float* sew  = (const float*)d_in[13];
  const float* seb  = (const float*)d_in[14];
  const float* g1   = (const float*)d_in[15];
  const float* g2   = (const float*)d_in[16];
  float* out = (float*)d_out;

  char* w = (char*)d_ws;
  auto take = [&](size_t bytes) -> char* {
    char* p = w; w += (bytes + 255) & ~(size_t)255; return p;
  };
  u16*  xt   = (u16*)  take(8388608);   // [4][4096][256] bf16 pixel-major
  u16*  q_t  = (u16*)  take(1048576);   // [4][4096][32] bf16
  u16*  k_t  = (u16*)  take(1048576);   // [4][4096][32] bf16
  u16*  v_c  = (u16*)  take(8388608);   // [4][256][4096] bf16 channel-major
  u16*  t1   = (u16*)  take(524288);    // [4][4096][16] bf16 (silu(conv1))
  u16*  y_t  = (u16*)  take(8388608);   // [4][4096][256] bf16 pixel-major
  float* O   = (float*)take(16777216);  // [4][4096][256] fp32 attention out, pixel-major
  u16*  w7t  = (u16*)  take(401408);
  u16*  w11t = (u16*)  take(991232);
  u16*  w1t  = (u16*)  take(73728);
  u16*  kwt  = (u16*)  take(16384);
  u16*  vwt  = (u16*)  take(131072);
  u16*  w2t  = (u16*)  take(81920);
  float* pooled = (float*)take(4096);
  float* gate   = (float*)take(4096);

  hipMemsetAsync(pooled, 0, 4096, stream);
  k_prep_w<<<3312, 256, 0, stream>>>(dw1w, dw2w, c1w, keyw, valw, c2w, w7t, w11t, w1t, kwt, vwt, w2t);
  k_prep_x<<<4096, 256, 0, stream>>>(x, xt);
  k_qconv<<<256, 256, 0, stream>>>(xt, w7t, w11t, w1t, dw1b, dw2b, c1b, q_t, t1);
  k_kv<<<256, 256, 0, stream>>>(xt, vwt, kwt, valb, keyb, v_c, k_t);
  k_attn<<<256, 512, 0, stream>>>(q_t, k_t, v_c, O);
  k_conv2<<<256, 256, 0, stream>>>(t1, w2t, c2b, y_t, pooled);
  k_se<<<4, 256, 0, stream>>>(pooled, sew, seb, gate);
  k_final<<<2048, 256, 0, stream>>>(O, y_t, x, gate, g1, g2, out);
}

// Round 2
// 508.810 us; speedup vs baseline: 1.2268x; 1.2268x over previous
//
#include <hip/hip_runtime.h>

typedef unsigned short u16;
typedef __bf16 bf16x8 __attribute__((ext_vector_type(8)));
typedef float f32x4 __attribute__((ext_vector_type(4)));

#define MFMA16(A,B,C) __builtin_amdgcn_mfma_f32_16x16x32_bf16((A),(B),(C),0,0,0)

__device__ __forceinline__ u16 f2b(float f){
  union { float f; unsigned u; } X; X.f = f;
  unsigned r = X.u + 0x7FFFu + ((X.u >> 16) & 1u);
  return (u16)(r >> 16);
}
__device__ __forceinline__ float b2f(u16 h){
  union { unsigned u; float f; } X; X.u = ((unsigned)h) << 16; return X.f;
}
__device__ __forceinline__ bf16x8 ld_frag(const u16* p){
  union { uint4 u; bf16x8 v; } U; U.u = *(const uint4*)p; return U.v;
}

// ---------------- K0: weight prep (transpose + bf16 cvt) ----------------
__global__ __launch_bounds__(256) void k_prep_w(
    const float* __restrict__ dw1, const float* __restrict__ dw2,
    const float* __restrict__ cw1, const float* __restrict__ kw,
    const float* __restrict__ vw,  const float* __restrict__ cw2,
    u16* __restrict__ w7t, u16* __restrict__ w11t, u16* __restrict__ w1t,
    u16* __restrict__ kwt, u16* __restrict__ vwt, u16* __restrict__ w2t){
  int i = blockIdx.x * 256 + threadIdx.x;
  const int N11 = 121*4096, N7 = 49*4096, N1 = 9*4096, NK = 8192, NV = 65536, N2 = 40960;
  if(i < N11){ int tap=i>>12, r=i&4095, oc=r>>8, ci=r&255; w11t[i] = f2b(dw2[(oc*256+ci)*121 + tap]); return; }
  i -= N11;
  if(i < N7){ int tap=i>>12, r=i&4095, oc=r>>8, ci=r&255; w7t[i] = f2b(dw1[(oc*256+ci)*49 + tap]); return; }
  i -= N7;
  if(i < N1){ int tap=i>>12, r=i&4095, oc=r>>8, ci=r&255; w1t[i] = f2b(cw1[(oc*256+ci)*9 + tap]); return; }
  i -= N1;
  if(i < NK){ kwt[i] = f2b(kw[i]); return; }
  i -= NK;
  if(i < NV){ vwt[i] = f2b(vw[i]); return; }
  i -= NV;
  if(i < N2){ int co = i/160, kk = i - co*160; w2t[i] = (kk < 144) ? f2b(cw2[co*144 + kk]) : (u16)0; return; }
}

// ---------------- K1: x NCHW fp32 -> padded xp[b][y+5][x+5][ci] bf16 ----------------
// xp dims [4][74][80][256]; halo pre-zeroed by memset.
__global__ __launch_bounds__(256) void k_prep_x(const float* __restrict__ x, u16* __restrict__ xp){
  __shared__ float tile[32][33];
  const int bid = blockIdx.x;
  const int b = bid >> 10, rem = bid & 1023;
  const int c0 = (rem >> 7) << 5, m0 = (rem & 127) << 5;
  const int t = threadIdx.x;
  { const int cg = t >> 5, mm = t & 31;
    #pragma unroll
    for(int i=0;i<4;i++)
      tile[cg*4+i][mm] = x[((size_t)(b*256 + c0 + cg*4 + i) << 12) + m0 + mm];
  }
  __syncthreads();
  { const int cp = (t & 15) << 1, mloc = t >> 4;
    #pragma unroll
    for(int half = 0; half < 2; ++half){
      const int ml = half*16 + mloc;
      const int m = m0 + ml;
      const int yy = (m >> 6) + 5, xx = (m & 63) + 5;
      u16 lo = f2b(tile[cp][ml]), hi = f2b(tile[cp+1][ml]);
      *(unsigned*)&xp[((size_t)(b*74 + yy)*80 + xx)*256 + c0 + cp] = ((unsigned)hi << 16) | lo;
    }
  }
}

// ---------------- K2: fused conv7+conv11+conv1 implicit GEMM, branch-free, ch-split ----------------
// grid 512 = (b,y,h); block 512 = 8 waves: wave = (pp px-pair, cs chunk-slot).
// fp32 partials qp[h][b*4096+px][48]: [0:16)=conv7, [16:32)=conv11, [32:48)=conv1.
__global__ __launch_bounds__(512, 4) void k_qconv(
    const u16* __restrict__ xp, const u16* __restrict__ w7t,
    const u16* __restrict__ w11t, const u16* __restrict__ w1t,
    float* __restrict__ qp){
  const int bid = blockIdx.x;
  const int h = bid & 1, y = (bid >> 1) & 63, b = bid >> 7;
  const int t = threadIdx.x, wv = t >> 6, lane = t & 63, col = lane & 15, quad = lane >> 4;
  const int pp = wv & 1, cs = wv >> 1;
  const int cio = (h*4 + cs)*32 + quad*8;
  const f32x4 z = {0.f,0.f,0.f,0.f};
  f32x4 a7[2] = {z,z}, a11[2] = {z,z}, a1[2] = {z,z};
  const u16* xb = xp + (size_t)(b*74)*20480 + cio;
  const int p0 = pp*32 + col;
  #pragma unroll 1
  for(int dy = 0; dy < 11; ++dy){
    const u16* xr = xb + (size_t)(y + dy)*20480;
    const bool in7y = (dy >= 2) & (dy <= 8);
    const bool in1y = (dy >= 4) & (dy <= 6);
    #pragma unroll
    for(int dx = 0; dx < 11; ++dx){
      bf16x8 A0 = ld_frag(xr + (p0 + dx)*256);
      bf16x8 A1 = ld_frag(xr + (p0 + 16 + dx)*256);
      bf16x8 wf11 = ld_frag(w11t + ((dy*11 + dx) << 12) + (col << 8) + cio);
      a11[0] = MFMA16(A0, wf11, a11[0]);
      a11[1] = MFMA16(A1, wf11, a11[1]);
      if(in7y && dx >= 2 && dx <= 8){
        bf16x8 wf7 = ld_frag(w7t + (((dy-2)*7 + (dx-2)) << 12) + (col << 8) + cio);
        a7[0] = MFMA16(A0, wf7, a7[0]);
        a7[1] = MFMA16(A1, wf7, a7[1]);
      }
      if(in1y && dx >= 4 && dx <= 6){
        bf16x8 wf1 = ld_frag(w1t + (((dy-4)*3 + (dx-4)) << 12) + (col << 8) + cio);
        a1[0] = MFMA16(A0, wf1, a1[0]);
        a1[1] = MFMA16(A1, wf1, a1[1]);
      }
    }
  }
  // reduce across the 4 cs-waves for each pp
  __shared__ __align__(16) f32x4 red[8][6][64];
  #pragma unroll
  for(int j = 0; j < 2; ++j){
    red[wv][j*3+0][lane] = a7[j];
    red[wv][j*3+1][lane] = a11[j];
    red[wv][j*3+2][lane] = a1[j];
  }
  __syncthreads();
  if(cs == 0){
    #pragma unroll
    for(int sw = 1; sw < 4; ++sw){
      const int w2 = pp + 2*sw;
      #pragma unroll
      for(int j = 0; j < 2; ++j){
        a7[j]  += red[w2][j*3+0][lane];
        a11[j] += red[w2][j*3+1][lane];
        a1[j]  += red[w2][j*3+2][lane];
      }
    }
    float* qb = qp + ((size_t)h*16384 + (b << 12) + (y << 6)) * 48;
    #pragma unroll
    for(int j = 0; j < 2; ++j){
      const int px = pp*32 + j*16 + quad*4;
      #pragma unroll
      for(int r = 0; r < 4; ++r){
        float* q = qb + (px + r)*48;
        q[col]      = a7[j][r];
        q[16 + col] = a11[j][r];
        q[32 + col] = a1[j][r];
      }
    }
  }
}

// ---------------- K2b: combine partials, bias, silu, bf16 ----------------
__global__ __launch_bounds__(256) void k_qfin(
    const float* __restrict__ qp, const float* __restrict__ b7,
    const float* __restrict__ b11, const float* __restrict__ b1,
    u16* __restrict__ q_t, u16* __restrict__ t1){
  const int t = threadIdx.x, wv = t >> 6, lane = t & 63;
  const int px = blockIdx.x*4 + wv;
  if(lane >= 48) return;
  float s = qp[(size_t)px*48 + lane] + qp[(size_t)(16384 + px)*48 + lane];
  if(lane < 16){
    q_t[px*32 + lane] = f2b(s + b7[lane]);
  } else if(lane < 32){
    q_t[px*32 + lane] = f2b(s + b11[lane - 16]);
  } else {
    float v = s + b1[lane - 32];
    t1[px*16 + lane - 32] = f2b(v / (1.f + __expf(-v)));
  }
}

// ---------------- K3: 1x1 convs from padded xp: k_t pixel-major, v_c channel-major ----------------
__global__ __launch_bounds__(256) void k_kv(
    const u16* __restrict__ xp, const u16* __restrict__ vwt, const u16* __restrict__ kwt,
    const float* __restrict__ vb, const float* __restrict__ kb,
    u16* __restrict__ v_c, u16* __restrict__ k_t){
  const int b = blockIdx.x >> 6, blk = blockIdx.x & 63;
  const int wv = threadIdx.x >> 6, lane = threadIdx.x & 63;
  const int col = lane & 15, quad = lane >> 4;
  const int m0 = (blk << 6) + (wv << 4);
  f32x4 z = {0.f,0.f,0.f,0.f};
  f32x4 av[16], ak[2];
  #pragma unroll
  for(int i=0;i<16;i++) av[i] = z;
  ak[0] = z; ak[1] = z;
  const int m = m0 + col;
  const u16* xrow = xp + ((size_t)(b*74 + (m >> 6) + 5)*80 + (m & 63) + 5)*256;
  #pragma unroll 1
  for(int ch = 0; ch < 8; ++ch){
    const int cio = ch*32 + quad*8;
    bf16x8 xf = ld_frag(xrow + cio);
    #pragma unroll
    for(int ct = 0; ct < 16; ++ct){
      bf16x8 wf = ld_frag(vwt + ((ct*16 + col) << 8) + cio);
      av[ct] = MFMA16(wf, xf, av[ct]);
    }
    #pragma unroll
    for(int kt = 0; kt < 2; ++kt){
      bf16x8 kf = ld_frag(kwt + ((kt*16 + col) << 8) + cio);
      ak[kt] = MFMA16(xf, kf, ak[kt]);
    }
  }
  #pragma unroll
  for(int ct = 0; ct < 16; ++ct){
    #pragma unroll
    for(int r = 0; r < 4; ++r){
      const int c = ct*16 + quad*4 + r;
      v_c[((size_t)(b*256 + c) << 12) + m0 + col] = f2b(av[ct][r] + vb[c]);
    }
  }
  #pragma unroll
  for(int kt = 0; kt < 2; ++kt){
    #pragma unroll
    for(int r = 0; r < 4; ++r){
      const int mq = b*4096 + m0 + quad*4 + r;
      k_t[mq*32 + kt*16 + col] = f2b(ak[kt][r] + kb[kt*16 + col]);
    }
  }
}

// ---------------- K4: flash attention. TQ=64/wg, TK=64, 8 waves ----------------
__global__ __launch_bounds__(512) void k_attn(
    const u16* __restrict__ q_t, const u16* __restrict__ k_t,
    const u16* __restrict__ v_c, u16* __restrict__ O){
  __shared__ __align__(16) float S[64][68];
  __shared__ __align__(16) u16 P[64][72];
  __shared__ float alpha_l[64];
  __shared__ float l_l[64];
  const int b = blockIdx.x >> 6, q0 = (blockIdx.x & 63) << 6;
  const int t = threadIdx.x, wv = t >> 6, lane = t & 63, col = lane & 15, quad = lane >> 4;
  const int qtw = wv >> 1;
  const int cb = wv << 5;
  const int sr = t >> 3, sc = t & 7;
  const bf16x8 qf = ld_frag(q_t + (size_t)(b*4096 + q0 + qtw*16 + col) * 32 + quad*8);
  const f32x4 z = {0.f,0.f,0.f,0.f};
  f32x4 acc[4][2];
  #pragma unroll
  for(int qq=0;qq<4;qq++){ acc[qq][0] = z; acc[qq][1] = z; }
  float m_i = -1e30f, l_i = 0.f;
  const u16* kbase = k_t + (size_t)(b*4096) * 32;
  const u16* vbase = v_c + ((size_t)(b*256 + cb) << 12);
  for(int kt = 0; kt < 64; ++kt){
    const int mm0 = kt << 6;
    { const int mt = (wv & 1) << 1;
      #pragma unroll
      for(int mi = 0; mi < 2; ++mi){
        bf16x8 kf = ld_frag(kbase + (size_t)(mm0 + (mt+mi)*16 + col) * 32 + quad*8);
        f32x4 s = MFMA16(qf, kf, z);
        const int rr = qtw*16 + quad*4, cc2 = (mt+mi)*16 + col;
        S[rr+0][cc2] = s[0]; S[rr+1][cc2] = s[1]; S[rr+2][cc2] = s[2]; S[rr+3][cc2] = s[3];
      }
    }
    __syncthreads();
    { float4 s0 = *(const float4*)&S[sr][sc*8];
      float4 s1 = *(const float4*)&S[sr][sc*8 + 4];
      float mx = fmaxf(fmaxf(fmaxf(s0.x,s0.y),fmaxf(s0.z,s0.w)),
                       fmaxf(fmaxf(s1.x,s1.y),fmaxf(s1.z,s1.w)));
      mx = fmaxf(mx, __shfl_xor(mx,1)); mx = fmaxf(mx, __shfl_xor(mx,2)); mx = fmaxf(mx, __shfl_xor(mx,4));
      const float mnew = fmaxf(m_i, mx);
      const float al = __expf(m_i - mnew);
      float p0 = __expf(s0.x - mnew), p1 = __expf(s0.y - mnew), p2 = __expf(s0.z - mnew), p3 = __expf(s0.w - mnew);
      float p4 = __expf(s1.x - mnew), p5 = __expf(s1.y - mnew), p6 = __expf(s1.z - mnew), p7 = __expf(s1.w - mnew);
      float sum = ((p0+p1)+(p2+p3)) + ((p4+p5)+(p6+p7));
      sum += __shfl_xor(sum,1); sum += __shfl_xor(sum,2); sum += __shfl_xor(sum,4);
      l_i = l_i * al + sum; m_i = mnew;
      union { u16 s[8]; uint4 u; } PW;
      PW.s[0]=f2b(p0); PW.s[1]=f2b(p1); PW.s[2]=f2b(p2); PW.s[3]=f2b(p3);
      PW.s[4]=f2b(p4); PW.s[5]=f2b(p5); PW.s[6]=f2b(p6); PW.s[7]=f2b(p7);
      *(uint4*)&P[sr][sc*8] = PW.u;
      if(sc == 0) alpha_l[sr] = al;
    }
    __syncthreads();
    { bf16x8 pa[4][2];
      #pragma unroll
      for(int qq=0; qq<4; ++qq)
        #pragma unroll
        for(int chh=0; chh<2; ++chh)
          pa[qq][chh] = ld_frag(&P[qq*16 + col][chh*32 + quad*8]);
      #pragma unroll
      for(int qq=0; qq<4; ++qq){
        f32x4 asc;
        asc[0] = alpha_l[qq*16 + quad*4 + 0];
        asc[1] = alpha_l[qq*16 + quad*4 + 1];
        asc[2] = alpha_l[qq*16 + quad*4 + 2];
        asc[3] = alpha_l[qq*16 + quad*4 + 3];
        acc[qq][0] *= asc; acc[qq][1] *= asc;
      }
      #pragma unroll
      for(int ct = 0; ct < 2; ++ct){
        #pragma unroll
        for(int chh = 0; chh < 2; ++chh){
          bf16x8 vf = ld_frag(vbase + ((size_t)(ct*16 + col) << 12) + mm0 + chh*32 + quad*8);
          #pragma unroll
          for(int qq = 0; qq < 4; ++qq)
            acc[qq][ct] = MFMA16(pa[qq][chh], vf, acc[qq][ct]);
        }
      }
    }
  }
  if(sc == 0) l_l[sr] = l_i;
  __syncthreads();
  #pragma unroll
  for(int qq = 0; qq < 4; ++qq){
    #pragma unroll
    for(int r = 0; r < 4; ++r){
      const float inv = 1.f / l_l[qq*16 + quad*4 + r];
      const int n = q0 + qq*16 + quad*4 + r;
      u16* orow = O + ((size_t)(b*4096 + n) << 8) + cb + col;
      orow[0]  = f2b(acc[qq][0][r] * inv);
      orow[16] = f2b(acc[qq][1][r] * inv);
    }
  }
}

// ---------------- K5: conv2 (3x3, 16->256) via LDS im2col + pooled partial sums ----------------
__global__ __launch_bounds__(256) void k_conv2(
    const u16* __restrict__ t1, const u16* __restrict__ w2t, const float* __restrict__ b2,
    u16* __restrict__ y_t, float* __restrict__ pooled){
  __shared__ __align__(16) u16 im[64][168];
  __shared__ float pool_l[256];
  const int b = blockIdx.x >> 6, y = blockIdx.x & 63;
  const int t = threadIdx.x;
  pool_l[t] = 0.f;
  const u16* t1b = t1 + ((size_t)(b*4096) << 4);
  for(int e = t; e < 64*144; e += 256){
    int px = e / 144, kk = e - px*144;
    int ci = kk / 9, tp = kk - ci*9;
    int ky = tp / 3, kx = tp - ky*3;
    int ryy = y + ky - 1, rxx = px + kx - 1;
    u16 val = 0;
    if((unsigned)ryy < 64u && (unsigned)rxx < 64u) val = t1b[((ryy<<6) + rxx)*16 + ci];
    im[px][kk] = val;
  }
  for(int e = t; e < 64*24; e += 256){ int px = e/24; im[px][144 + (e - px*24)] = 0; }
  __syncthreads();
  const int wv = t >> 6, lane = t & 63, col = lane & 15, quad = lane >> 4;
  const f32x4 z = {0.f,0.f,0.f,0.f};
  f32x4 acc[16];
  #pragma unroll
  for(int i=0;i<16;i++) acc[i] = z;
  #pragma unroll
  for(int ch = 0; ch < 5; ++ch){
    bf16x8 af = ld_frag(&im[wv*16 + col][ch*32 + quad*8]);
    #pragma unroll
    for(int nt = 0; nt < 16; ++nt){
      bf16x8 wf = ld_frag(w2t + (nt*16 + col)*160 + ch*32 + quad*8);
      acc[nt] = MFMA16(af, wf, acc[nt]);
    }
  }
  const int m0 = (y << 6) + (wv << 4) + (quad << 2);
  #pragma unroll
  for(int nt = 0; nt < 16; ++nt){
    const int c = nt*16 + col;
    const float bias = b2[c];
    float s = 0.f;
    #pragma unroll
    for(int r = 0; r < 4; ++r){
      float v = acc[nt][r] + bias;
      y_t[((size_t)(b*4096 + m0 + r) << 8) + c] = f2b(v);
      s += v;
    }
    s += __shfl_xor(s, 16); s += __shfl_xor(s, 32);
    if(quad == 0) atomicAdd(&pool_l[c], s);
  }
  __syncthreads();
  atomicAdd(&pooled[b*256 + t], pool_l[t]);
}

// ---------------- K6: SE gate ----------------
__global__ __launch_bounds__(256) void k_se(
    const float* __restrict__ pooled, const float* __restrict__ sew,
    const float* __restrict__ seb, float* __restrict__ g){
  __shared__ __align__(16) float pl[256];
  const int b = blockIdx.x, t = threadIdx.x;
  pl[t] = pooled[b*256 + t] * (1.f/4096.f);
  __syncthreads();
  float a = seb[t];
  const float4* wr = (const float4*)(sew + t*256);
  const float4* pr = (const float4*)pl;
  #pragma unroll 4
  for(int i = 0; i < 64; ++i){
    float4 w4 = wr[i]; float4 p4 = pr[i];
    a += w4.x*p4.x + w4.y*p4.y + w4.z*p4.z + w4.w*p4.w;
  }
  g[b*256 + t] = 1.f / (1.f + __expf(-a));
}

// ---------------- K7: final combine, pixel-major -> NCHW ----------------
__global__ __launch_bounds__(256) void k_final(
    const u16* __restrict__ O, const u16* __restrict__ y_t, const float* __restrict__ x,
    const float* __restrict__ g, const float* __restrict__ g1p, const float* __restrict__ g2p,
    float* __restrict__ out){
  __shared__ float tO[32][65];
  __shared__ float tY[32][65];
  const int bid = blockIdx.x;
  const int b = bid >> 9, rem = bid & 511;
  const int c0 = (rem >> 6) << 5, m0 = (rem & 63) << 6;
  const int t = threadIdx.x;
  const float g1 = g1p[0], g2 = g2p[0];
  { const int ml = t >> 2, cg = (t & 3) << 3;
    const u16* orow = O + ((size_t)(b*4096 + m0 + ml) << 8) + c0 + cg;
    uint4 ou = *(const uint4*)orow;
    tO[cg+0][ml]=b2f((u16)(ou.x & 0xffffu)); tO[cg+1][ml]=b2f((u16)(ou.x >> 16));
    tO[cg+2][ml]=b2f((u16)(ou.y & 0xffffu)); tO[cg+3][ml]=b2f((u16)(ou.y >> 16));
    tO[cg+4][ml]=b2f((u16)(ou.z & 0xffffu)); tO[cg+5][ml]=b2f((u16)(ou.z >> 16));
    tO[cg+6][ml]=b2f((u16)(ou.w & 0xffffu)); tO[cg+7][ml]=b2f((u16)(ou.w >> 16));
    const u16* yrow = y_t + ((size_t)(b*4096 + m0 + ml) << 8) + c0 + cg;
    uint4 yu = *(const uint4*)yrow;
    tY[cg+0][ml]=b2f((u16)(yu.x & 0xffffu)); tY[cg+1][ml]=b2f((u16)(yu.x >> 16));
    tY[cg+2][ml]=b2f((u16)(yu.y & 0xffffu)); tY[cg+3][ml]=b2f((u16)(yu.y >> 16));
    tY[cg+4][ml]=b2f((u16)(yu.z & 0xffffu)); tY[cg+5][ml]=b2f((u16)(yu.z >> 16));
    tY[cg+6][ml]=b2f((u16)(yu.w & 0xffffu)); tY[cg+7][ml]=b2f((u16)(yu.w >> 16));
  }
  __syncthreads();
  { const int cl = t >> 3, mg = (t & 7) << 3;
    const int c = c0 + cl;
    const float gate = g[b*256 + c] * g2;
    const float* xrow = x + ((size_t)(b*256 + c) << 12) + m0 + mg;
    float* orow = out + ((size_t)(b*256 + c) << 12) + m0 + mg;
    float4 x0 = *(const float4*)xrow, x1 = *(const float4*)(xrow + 4);
    float4 r0, r1;
    r0.x = g1*tO[cl][mg+0] + gate*tY[cl][mg+0] + x0.x;
    r0.y = g1*tO[cl][mg+1] + gate*tY[cl][mg+1] + x0.y;
    r0.z = g1*tO[cl][mg+2] + gate*tY[cl][mg+2] + x0.z;
    r0.w = g1*tO[cl][mg+3] + gate*tY[cl][mg+3] + x0.w;
    r1.x = g1*tO[cl][mg+4] + gate*tY[cl][mg+4] + x1.x;
    r1.y = g1*tO[cl][mg+5] + gate*tY[cl][mg+5] + x1.y;
    r1.z = g1*tO[cl][mg+6] + gate*tY[cl][mg+6] + x1.z;
    r1.w = g1*tO[cl][mg+7] + gate*tY[cl][mg+7] + x1.w;
    *(float4*)orow = r0;
    *(float4*)(orow + 4) = r1;
  }
}

extern "C" void kernel_launch(void* const* d_in, const int* in_sizes, int n_in,
                              void* d_out, int out_size, void* d_ws, size_t ws_size,
                              hipStream_t stream){
  (void)in_sizes; (void)n_in; (void)out_size; (void)ws_size;
  const float* x    = (const float*)d_in[0];
  const float* dw1w = (const float*)d_in[1];
  const float* dw1b = (const float*)d_in[2];
  const float* dw2w = (const float*)d_in[3];
  const float* dw2b = (const float*)d_in[4];
  const float* keyw = (const float*)d_in[5];
  const float* keyb = (const float*)d_in[6];
  const float* valw = (const float*)d_in[7];
  const float* valb = (const float*)d_in[8];
  const float* c1w  = (const float*)d_in[9];
  const float* c1b  = (const float*)d_in[10];
  const float* c2w  = (const float*)d_in[11];
  const float* c2b  = (const float*)d_in[12];
  const float* sew  = (const float*)d_in[13];
  const float* seb  = (const float*)d_in[14];
  const float* g1   = (const float*)d_in[15];
  const float* g2   = (const float*)d_in[16];
  float* out = (float*)d_out;

  char* w = (char*)d_ws;
  auto take = [&](size_t bytes) -> char* {
    char* p = w; w += (bytes + 255) & ~(size_t)255; return p;
  };
  u16*  xp   = (u16*)  take(12124160);  // [4][74][80][256] bf16, padded
  u16*  q_t  = (u16*)  take(1048576);   // [4][4096][32]
  u16*  k_t  = (u16*)  take(1048576);   // [4][4096][32]
  u16*  v_c  = (u16*)  take(8388608);   // [4][256][4096] channel-major
  u16*  t1   = (u16*)  take(524288);    // [4][4096][16]
  u16*  y_t  = (u16*)  take(8388608);   // [4][4096][256]; ALSO aliased as qp (disjoint live range)
  u16*  O    = (u16*)  take(8388608);   // [4][4096][256] bf16 attention out
  u16*  w7t  = (u16*)  take(401408);
  u16*  w11t = (u16*)  take(991232);
  u16*  w1t  = (u16*)  take(73728);
  u16*  kwt  = (u16*)  take(16384);
  u16*  vwt  = (u16*)  take(131072);
  u16*  w2t  = (u16*)  take(81920);
  float* pooled = (float*)take(4096);
  float* gate   = (float*)take(4096);
  float* qp = (float*)y_t;  // 6.29 MB partials live only between k_qconv and k_qfin

  hipMemsetAsync(xp, 0, 12124160, stream);
  hipMemsetAsync(pooled, 0, 4096, stream);
  k_prep_w<<<3312, 256, 0, stream>>>(dw1w, dw2w, c1w, keyw, valw, c2w, w7t, w11t, w1t, kwt, vwt, w2t);
  k_prep_x<<<4096, 256, 0, stream>>>(x, xp);
  k_qconv<<<512, 512, 0, stream>>>(xp, w7t, w11t, w1t, qp);
  k_qfin<<<4096, 256, 0, stream>>>(qp, dw1b, dw2b, c1b, q_t, t1);
  k_kv<<<256, 256, 0, stream>>>(xp, vwt, kwt, valb, keyb, v_c, k_t);
  k_attn<<<256, 512, 0, stream>>>(q_t, k_t, v_c, O);
  k_conv2<<<256, 256, 0, stream>>>(t1, w2t, c2b, y_t, pooled);
  k_se<<<4, 256, 0, stream>>>(pooled, sew, seb, gate);
  k_final<<<2048, 256, 0, stream>>>(O, y_t, x, gate, g1, g2, out);
}

// Round 3
// 447.213 us; speedup vs baseline: 1.3958x; 1.1377x over previous
//
#include <hip/hip_runtime.h>

typedef unsigned short u16;
typedef __bf16 bf16x8 __attribute__((ext_vector_type(8)));
typedef float f32x4 __attribute__((ext_vector_type(4)));
typedef float f32x16 __attribute__((ext_vector_type(16)));

#define MFMA16(A,B,C) __builtin_amdgcn_mfma_f32_16x16x32_bf16((A),(B),(C),0,0,0)
#define MFMA32(A,B,C) __builtin_amdgcn_mfma_f32_32x32x16_bf16((A),(B),(C),0,0,0)

__device__ __forceinline__ u16 f2b(float f){
  union { float f; unsigned u; } X; X.f = f;
  unsigned r = X.u + 0x7FFFu + ((X.u >> 16) & 1u);
  return (u16)(r >> 16);
}
__device__ __forceinline__ float b2f(u16 h){
  union { unsigned u; float f; } X; X.u = ((unsigned)h) << 16; return X.f;
}
__device__ __forceinline__ bf16x8 ld_frag(const u16* p){
  union { uint4 u; bf16x8 v; } U; U.u = *(const uint4*)p; return U.v;
}
__device__ __forceinline__ bf16x8 frag_of(uint4 u){
  union { uint4 u; bf16x8 v; } U; U.u = u; return U.v;
}

// ---------------- K0: weight prep ----------------
// wB[tap121][chunk16][oc32][ci16]: oc<16 -> conv7 (zero outside 7x7 window), oc>=16 -> conv11.
// wC[tap9][chunk16][oc32][ci16]:  oc<16 -> conv1, oc>=16 -> zero.
// kwt:[oc32][ci256]; vwt:[co256][ci256]; w2t:[co256][k160] (k=ci*9+tap, pad 144..159=0).
__global__ __launch_bounds__(256) void k_prep_w(
    const float* __restrict__ dw1, const float* __restrict__ dw2,
    const float* __restrict__ cw1, const float* __restrict__ kw,
    const float* __restrict__ vw,  const float* __restrict__ cw2,
    u16* __restrict__ wB, u16* __restrict__ wC,
    u16* __restrict__ kwt, u16* __restrict__ vwt, u16* __restrict__ w2t){
  int i = blockIdx.x * 256 + threadIdx.x;
  const int NB = 991232, NC = 73728, NK = 8192, NV = 65536, N2 = 40960;
  if(i < NB){
    int tap = i >> 13, rem = i & 8191;
    int chunk = rem >> 9, r2 = rem & 511;
    int oc = r2 >> 4, ci = chunk*16 + (r2 & 15);
    int dy = tap / 11, dx = tap - dy*11;
    float v;
    if(oc < 16){
      v = (dy >= 2 && dy <= 8 && dx >= 2 && dx <= 8) ? dw1[(oc*256 + ci)*49 + (dy-2)*7 + (dx-2)] : 0.f;
    } else {
      v = dw2[((oc-16)*256 + ci)*121 + tap];
    }
    wB[i] = f2b(v);
    return;
  }
  i -= NB;
  if(i < NC){
    int tap = i >> 13, rem = i & 8191;
    int chunk = rem >> 9, r2 = rem & 511;
    int oc = r2 >> 4, ci = chunk*16 + (r2 & 15);
    wC[i] = (oc < 16) ? f2b(cw1[(oc*256 + ci)*9 + tap]) : (u16)0;
    return;
  }
  i -= NC;
  if(i < NK){ kwt[i] = f2b(kw[i]); return; }
  i -= NK;
  if(i < NV){ vwt[i] = f2b(vw[i]); return; }
  i -= NV;
  if(i < N2){ int co = i/160, kk = i - co*160; w2t[i] = (kk < 144) ? f2b(cw2[co*144 + kk]) : (u16)0; return; }
}

// ---------------- K1: x NCHW fp32 -> padded xp[b][y+5][x+5][ci] bf16 ----------------
__global__ __launch_bounds__(256) void k_prep_x(const float* __restrict__ x, u16* __restrict__ xp){
  __shared__ float tile[32][33];
  const int bid = blockIdx.x;
  const int b = bid >> 10, rem = bid & 1023;
  const int c0 = (rem >> 7) << 5, m0 = (rem & 127) << 5;
  const int t = threadIdx.x;
  { const int cg = t >> 5, mm = t & 31;
    #pragma unroll
    for(int i=0;i<4;i++)
      tile[cg*4+i][mm] = x[((size_t)(b*256 + c0 + cg*4 + i) << 12) + m0 + mm];
  }
  __syncthreads();
  { const int cp = (t & 15) << 1, mloc = t >> 4;
    #pragma unroll
    for(int half = 0; half < 2; ++half){
      const int ml = half*16 + mloc;
      const int m = m0 + ml;
      const int yy = (m >> 6) + 5, xx = (m & 63) + 5;
      u16 lo = f2b(tile[cp][ml]), hi = f2b(tile[cp+1][ml]);
      *(unsigned*)&xp[((size_t)(b*74 + yy)*80 + xx)*256 + c0 + cp] = ((unsigned)hi << 16) | lo;
    }
  }
}

// ---------------- K2: fused conv7+conv11+conv1, 32x32x16 MFMA, LDS-staged x ----------------
// grid 256 = kq(4) x b(4) x rowgroup(16). block 512 = 8 waves, wave = 32px tile
// (yo = wv>>1 row, xo = (wv&1)*32). K-quarter kq: ci chunks [kq*4, kq*4+4) of 16.
// Partials qp[kq][16384][48] fp32: [0:16) conv7, [16:32) conv11, [32:48) conv1.
__global__ __launch_bounds__(512) void k_qconv(
    const u16* __restrict__ xp, const u16* __restrict__ wB, const u16* __restrict__ wC,
    float* __restrict__ qp){
  __shared__ __align__(16) u16 buf[2][17920];   // [14 rows][80 px][16 ci]
  const int bid = blockIdx.x;
  const int rg = bid & 15, b = (bid >> 4) & 3, kq = bid >> 6;
  const int y0 = rg << 2;
  const int t = threadIdx.x, wv = t >> 6, lane = t & 63;
  const int m = lane & 31, kh = lane >> 5;
  const int laneoff = m*16 + kh*8;
  const int yo = wv >> 1, xo = (wv & 1) << 5;
  const f32x16 z16 = {0.f,0.f,0.f,0.f,0.f,0.f,0.f,0.f,0.f,0.f,0.f,0.f,0.f,0.f,0.f,0.f};
  f32x16 acc = z16, acc1 = z16;

  const u16* xsrc = xp + ((size_t)(b*74 + y0)*80)*256;

  // stage chunk 0
  {
    const int ci0 = (kq*4 + 0) << 4;
    for(int e = t; e < 2240; e += 512){
      int row = e / 160, rem = e - row*160;
      int px = rem >> 1, half = rem & 1;
      uint4 v = *(const uint4*)(xsrc + ((size_t)row*80 + px)*256 + ci0 + half*8);
      ((uint4*)buf[0])[e] = v;
    }
  }
  __syncthreads();

  int cur = 0;
  #pragma unroll 1
  for(int c = 0; c < 4; ++c){
    uint4 nxt[5];
    int ne = 0;
    if(c < 3){
      const int ci0 = (kq*4 + c + 1) << 4;
      for(int e = t; e < 2240; e += 512){
        int row = e / 160, rem = e - row*160;
        int px = rem >> 1, half = rem & 1;
        nxt[ne++] = *(const uint4*)(xsrc + ((size_t)row*80 + px)*256 + ci0 + half*8);
      }
    }
    // compute on buf[cur], chunk = kq*4+c
    const int chunkg = kq*4 + c;
    const u16* wBc = wB + (size_t)chunkg*512 + laneoff;
    const u16* wCc = wC + (size_t)chunkg*512 + laneoff;
    #pragma unroll 1
    for(int dy = 0; dy < 11; ++dy){
      const u16* rowp = buf[cur] + (yo + dy)*1280 + xo*16 + laneoff;
      const u16* wrow = wBc + (size_t)(dy*11)*8192;
      const bool in1y = (dy >= 4) & (dy <= 6);
      #pragma unroll
      for(int dx = 0; dx < 11; ++dx){
        bf16x8 A = ld_frag(rowp + dx*16);
        bf16x8 B = ld_frag(wrow + (size_t)dx*8192);
        acc = MFMA32(A, B, acc);
        if(in1y && dx >= 4 && dx <= 6){
          bf16x8 B1 = ld_frag(wCc + (size_t)(((dy-4)*3 + (dx-4)) << 13));
          acc1 = MFMA32(A, B1, acc1);
        }
      }
    }
    if(c < 3){
      ne = 0;
      for(int e = t; e < 2240; e += 512){
        ((uint4*)buf[cur^1])[e] = nxt[ne++];
      }
    }
    __syncthreads();
    cur ^= 1;
  }

  // epilogue: D row=(reg&3)+8*(reg>>2)+4*(lane>>5) = px-in-tile, col=lane&31 = oc
  const int col = m;
  float* qb = qp + ((size_t)kq*16384 + (b << 12) + (y0 + yo)*64 + xo) * 48;
  #pragma unroll
  for(int reg = 0; reg < 16; ++reg){
    const int row = (reg & 3) + ((reg >> 2) << 3) + (kh << 2);
    qb[(size_t)row*48 + col] = acc[reg];
    if(col < 16) qb[(size_t)row*48 + 32 + col] = acc1[reg];
  }
}

// ---------------- K2b: combine 4 partials, bias, silu, bf16 ----------------
__global__ __launch_bounds__(256) void k_qfin(
    const float* __restrict__ qp, const float* __restrict__ b7,
    const float* __restrict__ b11, const float* __restrict__ b1,
    u16* __restrict__ q_t, u16* __restrict__ t1){
  const int t = threadIdx.x, wv = t >> 6, lane = t & 63;
  const int px = blockIdx.x*4 + wv;
  if(lane >= 48) return;
  const size_t off = (size_t)px*48 + lane;
  float s = qp[off] + qp[off + 786432] + qp[off + 2*786432] + qp[off + 3*786432];
  if(lane < 16){
    q_t[px*32 + lane] = f2b(s + b7[lane]);
  } else if(lane < 32){
    q_t[px*32 + lane] = f2b(s + b11[lane - 16]);
  } else {
    float v = s + b1[lane - 32];
    t1[px*16 + lane - 32] = f2b(v / (1.f + __expf(-v)));
  }
}

// ---------------- K3: 1x1 convs: k_t pixel-major, v_c channel-major ----------------
__global__ __launch_bounds__(256) void k_kv(
    const u16* __restrict__ xp, const u16* __restrict__ vwt, const u16* __restrict__ kwt,
    const float* __restrict__ vb, const float* __restrict__ kb,
    u16* __restrict__ v_c, u16* __restrict__ k_t){
  const int b = blockIdx.x >> 6, blk = blockIdx.x & 63;
  const int wv = threadIdx.x >> 6, lane = threadIdx.x & 63;
  const int col = lane & 15, quad = lane >> 4;
  const int m0 = (blk << 6) + (wv << 4);
  f32x4 z = {0.f,0.f,0.f,0.f};
  f32x4 av[16], ak[2];
  #pragma unroll
  for(int i=0;i<16;i++) av[i] = z;
  ak[0] = z; ak[1] = z;
  const int m = m0 + col;
  const u16* xrow = xp + ((size_t)(b*74 + (m >> 6) + 5)*80 + (m & 63) + 5)*256;
  #pragma unroll 1
  for(int ch = 0; ch < 8; ++ch){
    const int cio = ch*32 + quad*8;
    bf16x8 xf = ld_frag(xrow + cio);
    #pragma unroll
    for(int ct = 0; ct < 16; ++ct){
      bf16x8 wf = ld_frag(vwt + ((ct*16 + col) << 8) + cio);
      av[ct] = MFMA16(wf, xf, av[ct]);
    }
    #pragma unroll
    for(int kt = 0; kt < 2; ++kt){
      bf16x8 kf = ld_frag(kwt + ((kt*16 + col) << 8) + cio);
      ak[kt] = MFMA16(xf, kf, ak[kt]);
    }
  }
  #pragma unroll
  for(int ct = 0; ct < 16; ++ct){
    #pragma unroll
    for(int r = 0; r < 4; ++r){
      const int c = ct*16 + quad*4 + r;
      v_c[((size_t)(b*256 + c) << 12) + m0 + col] = f2b(av[ct][r] + vb[c]);
    }
  }
  #pragma unroll
  for(int kt = 0; kt < 2; ++kt){
    #pragma unroll
    for(int r = 0; r < 4; ++r){
      const int mq = b*4096 + m0 + quad*4 + r;
      k_t[mq*32 + kt*16 + col] = f2b(ak[kt][r] + kb[kt*16 + col]);
    }
  }
}

// ---------------- K4: flash attention. TQ=64/wg, TK=64, 8 waves ----------------
__global__ __launch_bounds__(512) void k_attn(
    const u16* __restrict__ q_t, const u16* __restrict__ k_t,
    const u16* __restrict__ v_c, u16* __restrict__ O){
  __shared__ __align__(16) float S[64][68];
  __shared__ __align__(16) u16 P[64][72];
  __shared__ float alpha_l[64];
  __shared__ float l_l[64];
  const int b = blockIdx.x >> 6, q0 = (blockIdx.x & 63) << 6;
  const int t = threadIdx.x, wv = t >> 6, lane = t & 63, col = lane & 15, quad = lane >> 4;
  const int qtw = wv >> 1;
  const int cb = wv << 5;
  const int sr = t >> 3, sc = t & 7;
  const bf16x8 qf = ld_frag(q_t + (size_t)(b*4096 + q0 + qtw*16 + col) * 32 + quad*8);
  const f32x4 z = {0.f,0.f,0.f,0.f};
  f32x4 acc[4][2];
  #pragma unroll
  for(int qq=0;qq<4;qq++){ acc[qq][0] = z; acc[qq][1] = z; }
  float m_i = -1e30f, l_i = 0.f;
  const u16* kbase = k_t + (size_t)(b*4096) * 32;
  const u16* vbase = v_c + ((size_t)(b*256 + cb) << 12);
  for(int kt = 0; kt < 64; ++kt){
    const int mm0 = kt << 6;
    { const int mt = (wv & 1) << 1;
      #pragma unroll
      for(int mi = 0; mi < 2; ++mi){
        bf16x8 kf = ld_frag(kbase + (size_t)(mm0 + (mt+mi)*16 + col) * 32 + quad*8);
        f32x4 s = MFMA16(qf, kf, z);
        const int rr = qtw*16 + quad*4, cc2 = (mt+mi)*16 + col;
        S[rr+0][cc2] = s[0]; S[rr+1][cc2] = s[1]; S[rr+2][cc2] = s[2]; S[rr+3][cc2] = s[3];
      }
    }
    __syncthreads();
    { float4 s0 = *(const float4*)&S[sr][sc*8];
      float4 s1 = *(const float4*)&S[sr][sc*8 + 4];
      float mx = fmaxf(fmaxf(fmaxf(s0.x,s0.y),fmaxf(s0.z,s0.w)),
                       fmaxf(fmaxf(s1.x,s1.y),fmaxf(s1.z,s1.w)));
      mx = fmaxf(mx, __shfl_xor(mx,1)); mx = fmaxf(mx, __shfl_xor(mx,2)); mx = fmaxf(mx, __shfl_xor(mx,4));
      const float mnew = fmaxf(m_i, mx);
      const float al = __expf(m_i - mnew);
      float p0 = __expf(s0.x - mnew), p1 = __expf(s0.y - mnew), p2 = __expf(s0.z - mnew), p3 = __expf(s0.w - mnew);
      float p4 = __expf(s1.x - mnew), p5 = __expf(s1.y - mnew), p6 = __expf(s1.z - mnew), p7 = __expf(s1.w - mnew);
      float sum = ((p0+p1)+(p2+p3)) + ((p4+p5)+(p6+p7));
      sum += __shfl_xor(sum,1); sum += __shfl_xor(sum,2); sum += __shfl_xor(sum,4);
      l_i = l_i * al + sum; m_i = mnew;
      union { u16 s[8]; uint4 u; } PW;
      PW.s[0]=f2b(p0); PW.s[1]=f2b(p1); PW.s[2]=f2b(p2); PW.s[3]=f2b(p3);
      PW.s[4]=f2b(p4); PW.s[5]=f2b(p5); PW.s[6]=f2b(p6); PW.s[7]=f2b(p7);
      *(uint4*)&P[sr][sc*8] = PW.u;
      if(sc == 0) alpha_l[sr] = al;
    }
    __syncthreads();
    { bf16x8 pa[4][2];
      #pragma unroll
      for(int qq=0; qq<4; ++qq)
        #pragma unroll
        for(int chh=0; chh<2; ++chh)
          pa[qq][chh] = ld_frag(&P[qq*16 + col][chh*32 + quad*8]);
      #pragma unroll
      for(int qq=0; qq<4; ++qq){
        f32x4 asc;
        asc[0] = alpha_l[qq*16 + quad*4 + 0];
        asc[1] = alpha_l[qq*16 + quad*4 + 1];
        asc[2] = alpha_l[qq*16 + quad*4 + 2];
        asc[3] = alpha_l[qq*16 + quad*4 + 3];
        acc[qq][0] *= asc; acc[qq][1] *= asc;
      }
      #pragma unroll
      for(int ct = 0; ct < 2; ++ct){
        #pragma unroll
        for(int chh = 0; chh < 2; ++chh){
          bf16x8 vf = ld_frag(vbase + ((size_t)(ct*16 + col) << 12) + mm0 + chh*32 + quad*8);
          #pragma unroll
          for(int qq = 0; qq < 4; ++qq)
            acc[qq][ct] = MFMA16(pa[qq][chh], vf, acc[qq][ct]);
        }
      }
    }
  }
  if(sc == 0) l_l[sr] = l_i;
  __syncthreads();
  #pragma unroll
  for(int qq = 0; qq < 4; ++qq){
    #pragma unroll
    for(int r = 0; r < 4; ++r){
      const float inv = 1.f / l_l[qq*16 + quad*4 + r];
      const int n = q0 + qq*16 + quad*4 + r;
      u16* orow = O + ((size_t)(b*4096 + n) << 8) + cb + col;
      orow[0]  = f2b(acc[qq][0][r] * inv);
      orow[16] = f2b(acc[qq][1][r] * inv);
    }
  }
}

// ---------------- K5: conv2 (3x3, 16->256) via LDS im2col + pooled partial sums ----------------
__global__ __launch_bounds__(256) void k_conv2(
    const u16* __restrict__ t1, const u16* __restrict__ w2t, const float* __restrict__ b2,
    u16* __restrict__ y_t, float* __restrict__ pooled){
  __shared__ __align__(16) u16 im[64][168];
  __shared__ float pool_l[256];
  const int b = blockIdx.x >> 6, y = blockIdx.x & 63;
  const int t = threadIdx.x;
  pool_l[t] = 0.f;
  const u16* t1b = t1 + ((size_t)(b*4096) << 4);
  for(int e = t; e < 64*144; e += 256){
    int px = e / 144, kk = e - px*144;
    int ci = kk / 9, tp = kk - ci*9;
    int ky = tp / 3, kx = tp - ky*3;
    int ryy = y + ky - 1, rxx = px + kx - 1;
    u16 val = 0;
    if((unsigned)ryy < 64u && (unsigned)rxx < 64u) val = t1b[((ryy<<6) + rxx)*16 + ci];
    im[px][kk] = val;
  }
  for(int e = t; e < 64*24; e += 256){ int px = e/24; im[px][144 + (e - px*24)] = 0; }
  __syncthreads();
  const int wv = t >> 6, lane = t & 63, col = lane & 15, quad = lane >> 4;
  const f32x4 z = {0.f,0.f,0.f,0.f};
  f32x4 acc[16];
  #pragma unroll
  for(int i=0;i<16;i++) acc[i] = z;
  #pragma unroll
  for(int ch = 0; ch < 5; ++ch){
    bf16x8 af = ld_frag(&im[wv*16 + col][ch*32 + quad*8]);
    #pragma unroll
    for(int nt = 0; nt < 16; ++nt){
      bf16x8 wf = ld_frag(w2t + (nt*16 + col)*160 + ch*32 + quad*8);
      acc[nt] = MFMA16(af, wf, acc[nt]);
    }
  }
  const int m0 = (y << 6) + (wv << 4) + (quad << 2);
  #pragma unroll
  for(int nt = 0; nt < 16; ++nt){
    const int c = nt*16 + col;
    const float bias = b2[c];
    float s = 0.f;
    #pragma unroll
    for(int r = 0; r < 4; ++r){
      float v = acc[nt][r] + bias;
      y_t[((size_t)(b*4096 + m0 + r) << 8) + c] = f2b(v);
      s += v;
    }
    s += __shfl_xor(s, 16); s += __shfl_xor(s, 32);
    if(quad == 0) atomicAdd(&pool_l[c], s);
  }
  __syncthreads();
  atomicAdd(&pooled[b*256 + t], pool_l[t]);
}

// ---------------- K6: SE gate ----------------
__global__ __launch_bounds__(256) void k_se(
    const float* __restrict__ pooled, const float* __restrict__ sew,
    const float* __restrict__ seb, float* __restrict__ g){
  __shared__ __align__(16) float pl[256];
  const int b = blockIdx.x, t = threadIdx.x;
  pl[t] = pooled[b*256 + t] * (1.f/4096.f);
  __syncthreads();
  float a = seb[t];
  const float4* wr = (const float4*)(sew + t*256);
  const float4* pr = (const float4*)pl;
  #pragma unroll 4
  for(int i = 0; i < 64; ++i){
    float4 w4 = wr[i]; float4 p4 = pr[i];
    a += w4.x*p4.x + w4.y*p4.y + w4.z*p4.z + w4.w*p4.w;
  }
  g[b*256 + t] = 1.f / (1.f + __expf(-a));
}

// ---------------- K7: final combine, pixel-major -> NCHW ----------------
__global__ __launch_bounds__(256) void k_final(
    const u16* __restrict__ O, const u16* __restrict__ y_t, const float* __restrict__ x,
    const float* __restrict__ g, const float* __restrict__ g1p, const float* __restrict__ g2p,
    float* __restrict__ out){
  __shared__ float tO[32][65];
  __shared__ float tY[32][65];
  const int bid = blockIdx.x;
  const int b = bid >> 9, rem = bid & 511;
  const int c0 = (rem >> 6) << 5, m0 = (rem & 63) << 6;
  const int t = threadIdx.x;
  const float g1 = g1p[0], g2 = g2p[0];
  { const int ml = t >> 2, cg = (t & 3) << 3;
    const u16* orow = O + ((size_t)(b*4096 + m0 + ml) << 8) + c0 + cg;
    uint4 ou = *(const uint4*)orow;
    tO[cg+0][ml]=b2f((u16)(ou.x & 0xffffu)); tO[cg+1][ml]=b2f((u16)(ou.x >> 16));
    tO[cg+2][ml]=b2f((u16)(ou.y & 0xffffu)); tO[cg+3][ml]=b2f((u16)(ou.y >> 16));
    tO[cg+4][ml]=b2f((u16)(ou.z & 0xffffu)); tO[cg+5][ml]=b2f((u16)(ou.z >> 16));
    tO[cg+6][ml]=b2f((u16)(ou.w & 0xffffu)); tO[cg+7][ml]=b2f((u16)(ou.w >> 16));
    const u16* yrow = y_t + ((size_t)(b*4096 + m0 + ml) << 8) + c0 + cg;
    uint4 yu = *(const uint4*)yrow;
    tY[cg+0][ml]=b2f((u16)(yu.x & 0xffffu)); tY[cg+1][ml]=b2f((u16)(yu.x >> 16));
    tY[cg+2][ml]=b2f((u16)(yu.y & 0xffffu)); tY[cg+3][ml]=b2f((u16)(yu.y >> 16));
    tY[cg+4][ml]=b2f((u16)(yu.z & 0xffffu)); tY[cg+5][ml]=b2f((u16)(yu.z >> 16));
    tY[cg+6][ml]=b2f((u16)(yu.w & 0xffffu)); tY[cg+7][ml]=b2f((u16)(yu.w >> 16));
  }
  __syncthreads();
  { const int cl = t >> 3, mg = (t & 7) << 3;
    const int c = c0 + cl;
    const float gate = g[b*256 + c] * g2;
    const float* xrow = x + ((size_t)(b*256 + c) << 12) + m0 + mg;
    float* orow = out + ((size_t)(b*256 + c) << 12) + m0 + mg;
    float4 x0 = *(const float4*)xrow, x1 = *(const float4*)(xrow + 4);
    float4 r0, r1;
    r0.x = g1*tO[cl][mg+0] + gate*tY[cl][mg+0] + x0.x;
    r0.y = g1*tO[cl][mg+1] + gate*tY[cl][mg+1] + x0.y;
    r0.z = g1*tO[cl][mg+2] + gate*tY[cl][mg+2] + x0.z;
    r0.w = g1*tO[cl][mg+3] + gate*tY[cl][mg+3] + x0.w;
    r1.x = g1*tO[cl][mg+4] + gate*tY[cl][mg+4] + x1.x;
    r1.y = g1*tO[cl][mg+5] + gate*tY[cl][mg+5] + x1.y;
    r1.z = g1*tO[cl][mg+6] + gate*tY[cl][mg+6] + x1.z;
    r1.w = g1*tO[cl][mg+7] + gate*tY[cl][mg+7] + x1.w;
    *(float4*)orow = r0;
    *(float4*)(orow + 4) = r1;
  }
}

extern "C" void kernel_launch(void* const* d_in, const int* in_sizes, int n_in,
                              void* d_out, int out_size, void* d_ws, size_t ws_size,
                              hipStream_t stream){
  (void)in_sizes; (void)n_in; (void)out_size; (void)ws_size;
  const float* x    = (const float*)d_in[0];
  const float* dw1w = (const float*)d_in[1];
  const float* dw1b = (const float*)d_in[2];
  const float* dw2w = (const float*)d_in[3];
  const float* dw2b = (const float*)d_in[4];
  const float* keyw = (const float*)d_in[5];
  const float* keyb = (const float*)d_in[6];
  const float* valw = (const float*)d_in[7];
  const float* valb = (const float*)d_in[8];
  const float* c1w  = (const float*)d_in[9];
  const float* c1b  = (const float*)d_in[10];
  const float* c2w  = (const float*)d_in[11];
  const float* c2b  = (const float*)d_in[12];
  const float* sew  = (const float*)d_in[13];
  const float* seb  = (const float*)d_in[14];
  const float* g1   = (const float*)d_in[15];
  const float* g2   = (const float*)d_in[16];
  float* out = (float*)d_out;

  char* w = (char*)d_ws;
  auto take = [&](size_t bytes) -> char* {
    char* p = w; w += (bytes + 255) & ~(size_t)255; return p;
  };
  u16*  xp   = (u16*)  take(12124160);  // [4][74][80][256] bf16, padded
  u16*  q_t  = (u16*)  take(1048576);   // [4][4096][32]
  u16*  k_t  = (u16*)  take(1048576);   // [4][4096][32]
  u16*  v_c  = (u16*)  take(8388608);   // [4][256][4096] channel-major
  u16*  t1   = (u16*)  take(524288);    // [4][4096][16]
  u16*  y_t  = (u16*)  take(8388608);   // [4][4096][256]; y_t+O also alias qp (disjoint live range)
  u16*  O    = (u16*)  take(8388608);   // [4][4096][256] bf16 attention out
  u16*  wB   = (u16*)  take(1982464);   // [121][16][32][16]
  u16*  wC   = (u16*)  take(147456);    // [9][16][32][16]
  u16*  kwt  = (u16*)  take(16384);
  u16*  vwt  = (u16*)  take(131072);
  u16*  w2t  = (u16*)  take(81920);
  float* pooled = (float*)take(4096);
  float* gate   = (float*)take(4096);
  float* qp = (float*)y_t;  // 12.6 MB partials live only between k_qconv and k_qfin (spans y_t+O)

  hipMemsetAsync(xp, 0, 12124160, stream);
  hipMemsetAsync(pooled, 0, 4096, stream);
  k_prep_w<<<4608, 256, 0, stream>>>(dw1w, dw2w, c1w, keyw, valw, c2w, wB, wC, kwt, vwt, w2t);
  k_prep_x<<<4096, 256, 0, stream>>>(x, xp);
  k_qconv<<<256, 512, 0, stream>>>(xp, wB, wC, qp);
  k_qfin<<<4096, 256, 0, stream>>>(qp, dw1b, dw2b, c1b, q_t, t1);
  k_kv<<<256, 256, 0, stream>>>(xp, vwt, kwt, valb, keyb, v_c, k_t);
  k_attn<<<256, 512, 0, stream>>>(q_t, k_t, v_c, O);
  k_conv2<<<256, 256, 0, stream>>>(t1, w2t, c2b, y_t, pooled);
  k_se<<<4, 256, 0, stream>>>(pooled, sew, seb, gate);
  k_final<<<2048, 256, 0, stream>>>(O, y_t, x, gate, g1, g2, out);
}